// Round 2
// baseline (334.224 us; speedup 1.0000x reference)
//
#include <hip/hip_runtime.h>

// LIF scan: x[B,T,N] f32 -> spikes[B,T,N] f32
//   v = v + (x - v)/2 ; s = (v >= 1) ; v = s ? 0 : v
// Sequential in t only; B*N independent chains. Memory-bound streaming
// (~420 MB total traffic -> ~67 us floor at 6.3 TB/s copy ceiling).
//
// R2 change vs R1: float2 -> scalar f32 chain granularity.
//   Ladder: float4 (4 waves/CU) = ~80 us, float2 (8 waves/CU) = ~75 us.
//   Still 5.6 TB/s vs 6.3 ceiling with VALUBusy tiny -> latency-bound,
//   not issue-bound. Scalar f32 doubles TLP again: 262144 threads ->
//   1024 blocks -> 4 blocks/CU -> 16 waves/CU (4/SIMD). Wave loads are
//   still perfectly coalesced (256 B contiguous per instruction).
//   Nontemporal hints kept: both streams are touch-once.

constexpr int B = 64;
constexpr int T = 200;
constexpr int N = 4096;

__global__ __launch_bounds__(256) void lif_kernel(const float* __restrict__ x,
                                                  float* __restrict__ out) {
    const int idx = blockIdx.x * blockDim.x + threadIdx.x;  // 0 .. B*N-1
    const int b = idx >> 12;        // idx / N
    const int n = idx & (N - 1);    // idx % N

    const float* __restrict__ xp = x + (size_t)b * (T * N) + n;
    float* __restrict__ op = out + (size_t)b * (T * N) + n;

    float v = 0.0f;

#pragma unroll 8
    for (int t = 0; t < T; ++t) {
        const float xv = __builtin_nontemporal_load(xp + t * N);
        // v = v + (x - v) * 0.5f  -- *0.5 is exact (power of two), so with
        // or without fma contraction this matches the f32 reference
        // bit-for-bit (absmax == 0.0 verified in R0/R1 with this form).
        v = v + (xv - v) * 0.5f;
        const float s = (v >= 1.0f) ? 1.0f : 0.0f;
        v = (v >= 1.0f) ? 0.0f : v;
        __builtin_nontemporal_store(s, op + t * N);
    }
}

extern "C" void kernel_launch(void* const* d_in, const int* in_sizes, int n_in,
                              void* d_out, int out_size, void* d_ws, size_t ws_size,
                              hipStream_t stream) {
    const float* x = (const float*)d_in[0];  // [B,T,N] f32
    // d_in[1] (threshold, 1xN) is unused by the reference math.
    float* out = (float*)d_out;

    const int threads = B * N;         // 262144 chains (scalar granularity)
    const int block = 256;
    const int grid = threads / block;  // 1024 blocks -> 4 blocks/CU, 16 waves/CU
    lif_kernel<<<grid, block, 0, stream>>>(x, out);
}